// Round 2
// baseline (1066.919 us; speedup 1.0000x reference)
//
#include <hip/hip_runtime.h>

// Problem constants
#define KCB   1024      // codebook size
#define DCV   64        // code dim
#define NB    32        // batch
#define HWN   4096      // H*W
#define CHW   262144    // DCV*HWN
#define NTOT  131072    // NB*HWN

// Output offsets (floats), concatenated in reference return order
#define O_ZQ   0
#define O_IDX  8388608
#define O_LOSS 8519680
#define O_NE   8519681
#define O_NCS  8585217
#define O_NEA  8586241

// Workspace byte offsets
#define W_LOSS  0                       // double
#define W_CTR   64                      // int refine counter
#define W_E2    256                     // 4 KB
#define W_SM    (256 + 4096)            // 4 KB
#define W_IDX   (256 + 8192)            // 512 KB int
#define W_RLIST (256 + 8192 + 4*NTOT)   // up to 512 KB int

#define MARGIN 0.03f

// ---------------------------------------------------------------------------
// K0: init accumulated outputs + precompute ||e||^2 + zero scalars
// ---------------------------------------------------------------------------
__global__ __launch_bounds__(256) void k_init(
    const float* __restrict__ emb, const float* __restrict__ cs,
    const float* __restrict__ ea, float* __restrict__ out,
    float* __restrict__ e2, double* __restrict__ loss, int* __restrict__ ctr)
{
    int j = blockIdx.x * 256 + threadIdx.x;
    if (j < KCB * DCV) out[O_NEA + j] = 0.99f * ea[j];
    if (j < KCB) {
        out[O_NCS + j] = 0.99f * cs[j];
        const float* er = emb + j * DCV;
        float s = 0.f;
        #pragma unroll
        for (int d = 0; d < DCV; ++d) { float v = er[d]; s = fmaf(v, v, s); }
        e2[j] = s;
    }
    if (j == 0) { *loss = 0.0; *ctr = 0; }
}

// ---------------------------------------------------------------------------
// K1a: f32 argmin prefilter. Tracks best + second-best; near-ties flagged
// for fp64 refinement.
// ---------------------------------------------------------------------------
__global__ __launch_bounds__(256) void k_argmin(
    const float* __restrict__ ze, const float* __restrict__ emb,
    const float* __restrict__ e2g, int* __restrict__ idxws,
    int* __restrict__ ctr, int* __restrict__ rlist)
{
    int n  = blockIdx.x * 256 + threadIdx.x;
    int b  = n >> 12;
    int hw = n & 4095;
    const float* zp = ze + (size_t)b * CHW + hw;

    float x[DCV];
    #pragma unroll
    for (int d = 0; d < DCV; ++d) x[d] = zp[d * HWN];

    float x2 = 0.f;
    #pragma unroll
    for (int d = 0; d < DCV; ++d) x2 = fmaf(x[d], x[d], x2);

    int   best  = 0;
    float bestd = 3.4e38f, second = 3.4e38f;
    #pragma unroll 1
    for (int k = 0; k < KCB; ++k) {
        const float* eb = emb + k * DCV;
        float a0 = 0.f, a1 = 0.f, a2 = 0.f, a3 = 0.f;
        #pragma unroll
        for (int d = 0; d < DCV; d += 4) {
            a0 = fmaf(x[d + 0], eb[d + 0], a0);
            a1 = fmaf(x[d + 1], eb[d + 1], a1);
            a2 = fmaf(x[d + 2], eb[d + 2], a2);
            a3 = fmaf(x[d + 3], eb[d + 3], a3);
        }
        float dot  = (a0 + a1) + (a2 + a3);
        float dist = fmaf(-2.f, dot, x2 + e2g[k]);
        if (dist < bestd)       { second = bestd; bestd = dist; best = k; }
        else if (dist < second) { second = dist; }
    }

    idxws[n] = best;
    if (second - bestd < MARGIN) {
        int p = atomicAdd(ctr, 1);
        rlist[p] = n;
    }
}

// ---------------------------------------------------------------------------
// K1b: fp64 exact argmin for flagged vectors. One wave per candidate;
// lane l handles codes {c*64+l}. Smallest-index tie-break.
// ---------------------------------------------------------------------------
__global__ __launch_bounds__(256) void k_refine(
    const float* __restrict__ ze, const float* __restrict__ emb,
    int* __restrict__ idxws, const int* __restrict__ ctr,
    const int* __restrict__ rlist)
{
    int lane = threadIdx.x & 63;
    int gw   = (blockIdx.x * blockDim.x + threadIdx.x) >> 6;
    int nw   = (gridDim.x * blockDim.x) >> 6;
    int cnt  = *ctr;

    for (int i = gw; i < cnt; i += nw) {
        int n  = rlist[i];
        int b  = n >> 12;
        int hw = n & 4095;
        const float* zp = ze + (size_t)b * CHW + hw;

        float x[DCV];
        #pragma unroll
        for (int d = 0; d < DCV; ++d) x[d] = zp[d * HWN];  // same addr all lanes -> broadcast

        double bd = 1e300;
        int    bi = 0;
        #pragma unroll 1
        for (int c = 0; c < KCB / 64; ++c) {
            int k = c * 64 + lane;
            const float* eb = emb + k * DCV;
            double a0 = 0.0, a1 = 0.0;
            #pragma unroll
            for (int d = 0; d < DCV; d += 2) {
                double d0 = (double)x[d]     - (double)eb[d];
                double d1 = (double)x[d + 1] - (double)eb[d + 1];
                a0 = fma(d0, d0, a0);
                a1 = fma(d1, d1, a1);
            }
            double dist = a0 + a1;
            if (dist < bd || (dist == bd && k < bi)) { bd = dist; bi = k; }
        }
        #pragma unroll
        for (int off = 32; off > 0; off >>= 1) {
            double od = __shfl_xor(bd, off, 64);
            int    oi = __shfl_xor(bi, off, 64);
            if (od < bd || (od == bd && oi < bi)) { bd = od; bi = oi; }
        }
        if (lane == 0) idxws[n] = bi;
    }
}

// ---------------------------------------------------------------------------
// K1c: finalize from final indices: z_q_st write, indices-as-float write,
// commitment-loss partial, count histogram.
// ---------------------------------------------------------------------------
__global__ __launch_bounds__(256) void k_final(
    const float* __restrict__ ze, const float* __restrict__ emb,
    const int* __restrict__ idxws, float* __restrict__ out,
    double* __restrict__ loss)
{
    int n  = blockIdx.x * 256 + threadIdx.x;
    int b  = n >> 12;
    int hw = n & 4095;
    int best = idxws[n];
    out[O_IDX + n] = (float)best;

    const float* zp = ze + (size_t)b * CHW + hw;
    const float4* er4 = (const float4*)(emb + best * DCV);
    float er[DCV];
    #pragma unroll
    for (int q = 0; q < DCV / 4; ++q) {
        float4 v = er4[q];
        er[q * 4 + 0] = v.x; er[q * 4 + 1] = v.y;
        er[q * 4 + 2] = v.z; er[q * 4 + 3] = v.w;
    }

    float* zq = out + O_ZQ + (size_t)b * CHW + hw;
    float lp = 0.f;
    #pragma unroll
    for (int d = 0; d < DCV; ++d) {
        float x  = zp[d * HWN];
        float df = x - er[d];          // == -(stop_grad diff)
        lp = fmaf(df, df, lp);
        zq[d * HWN] = x + (er[d] - x); // mimic straight-through f32 rounding
    }

    #pragma unroll
    for (int off = 32; off > 0; off >>= 1) lp += __shfl_down(lp, off, 64);

    __shared__ int   hist[KCB];
    __shared__ float wsum[4];
    for (int i = threadIdx.x; i < KCB; i += 256) hist[i] = 0;
    __syncthreads();
    int lane = threadIdx.x & 63, wid = threadIdx.x >> 6;
    if (lane == 0) wsum[wid] = lp;
    atomicAdd(&hist[best], 1);
    __syncthreads();
    if (threadIdx.x == 0) {
        double s = (double)wsum[0] + wsum[1] + wsum[2] + wsum[3];
        atomicAdd(loss, s);
    }
    for (int i = threadIdx.x; i < KCB; i += 256) {
        int c = hist[i];
        if (c) atomicAdd(&out[O_NCS + i], 0.01f * (float)c);
    }
}

// ---------------------------------------------------------------------------
// K2: dw = segment_sum(flat, idx) accumulated as 0.01*dw into new_embed_avg.
// ---------------------------------------------------------------------------
__global__ __launch_bounds__(256) void k_dw(
    const float* __restrict__ ze, const int* __restrict__ idxws,
    float* __restrict__ out)
{
    int g = blockIdx.x >> 5;   // dim group (8 dims)
    int b = blockIdx.x & 31;   // batch
    __shared__ float acc[KCB * 8];
    for (int i = threadIdx.x; i < KCB * 8; i += 256) acc[i] = 0.f;
    __syncthreads();

    const float* zp = ze + (size_t)b * CHW + (size_t)g * 8 * HWN;
    const int*   ip = idxws + b * HWN;
    for (int v0 = 0; v0 < HWN; v0 += 256) {
        int hw  = v0 + threadIdx.x;
        int idx = ip[hw];
        #pragma unroll
        for (int i = 0; i < 8; ++i) {
            float val = zp[i * HWN + hw];
            atomicAdd(&acc[idx * 8 + i], val);
        }
    }
    __syncthreads();
    for (int j = threadIdx.x; j < KCB * 8; j += 256) {
        int k = j >> 3, i = j & 7;
        atomicAdd(&out[O_NEA + k * DCV + g * 8 + i], 0.01f * acc[j]);
    }
}

// ---------------------------------------------------------------------------
// K3: n = sum(new_cluster_size); smoothed denom; loss scalar
// ---------------------------------------------------------------------------
__global__ __launch_bounds__(1024) void k_stats(
    float* __restrict__ out, float* __restrict__ sm,
    const double* __restrict__ loss)
{
    int k = threadIdx.x;
    float ncs = out[O_NCS + k];
    __shared__ float red[KCB];
    red[k] = ncs;
    __syncthreads();
    for (int s = 512; s > 0; s >>= 1) {
        if (k < s) red[k] += red[k + s];
        __syncthreads();
    }
    float n = red[0];
    sm[k] = (ncs + 1e-5f) / (n + (float)KCB * 1e-5f) * n;
    if (k == 0) out[O_LOSS] = (float)(0.25 * (*loss) / (double)(NTOT * DCV));
}

// ---------------------------------------------------------------------------
// K4: new_embedding = new_embed_avg / smoothed[k]
// ---------------------------------------------------------------------------
__global__ __launch_bounds__(256) void k_embed(
    float* __restrict__ out, const float* __restrict__ sm)
{
    int j = blockIdx.x * 256 + threadIdx.x;
    if (j < KCB * DCV) out[O_NE + j] = out[O_NEA + j] / sm[j >> 6];
}

// ---------------------------------------------------------------------------
extern "C" void kernel_launch(void* const* d_in, const int* in_sizes, int n_in,
                              void* d_out, int out_size, void* d_ws, size_t ws_size,
                              hipStream_t stream)
{
    const float* ze  = (const float*)d_in[0];   // [32,64,64,64]
    const float* emb = (const float*)d_in[1];   // [1024,64]
    const float* cs  = (const float*)d_in[2];   // [1024]
    const float* ea  = (const float*)d_in[3];   // [1024,64]
    float* out = (float*)d_out;

    char*   w     = (char*)d_ws;
    double* loss  = (double*)(w + W_LOSS);
    int*    ctr   = (int*)(w + W_CTR);
    float*  e2    = (float*)(w + W_E2);
    float*  sm    = (float*)(w + W_SM);
    int*    idxws = (int*)(w + W_IDX);
    int*    rlist = (int*)(w + W_RLIST);

    k_init  <<<256, 256, 0, stream>>>(emb, cs, ea, out, e2, loss, ctr);
    k_argmin<<<NTOT / 256, 256, 0, stream>>>(ze, emb, e2, idxws, ctr, rlist);
    k_refine<<<256, 256, 0, stream>>>(ze, emb, idxws, ctr, rlist);
    k_final <<<NTOT / 256, 256, 0, stream>>>(ze, emb, idxws, out, loss);
    k_dw    <<<256, 256, 0, stream>>>(ze, idxws, out);
    k_stats <<<1, 1024, 0, stream>>>(out, sm, loss);
    k_embed <<<256, 256, 0, stream>>>(out, sm);
}

// Round 4
// 292.499 us; speedup vs baseline: 3.6476x; 3.6476x over previous
//
#include <hip/hip_runtime.h>

// Problem constants
#define KCB   1024      // codebook size
#define DCV   64        // code dim
#define HWN   4096      // H*W
#define CHW   262144    // DCV*HWN per batch
#define NTOT  131072    // 32*HWN

// Output offsets (floats), concatenated in reference return order
#define O_ZQ   0
#define O_IDX  8388608
#define O_LOSS 8519680
#define O_NE   8519681
#define O_NCS  8585217
#define O_NEA  8586241

// Workspace byte offsets — TOTAL FOOTPRINT 925,952 B < 1 MiB.
// (Round-3 failure root-caused to ws overflow: offsets past ~1 MiB were
// written every launch and corrupted the harness's pristine input copy.)
#define W_LOSS  0                 // 8 B   double
#define W_CTR   64                // 4 B   int
#define W_E2    256               // 4 KB
#define W_SM    4352              // 4 KB
#define W_HIT   8448              // 128 KB bf16-hi codebook [q][code][8]
#define W_LOT   139520            // 128 KB bf16-lo codebook
#define W_PARTC 270592            // 128 KB per-batch count partials
#define W_RLIST 401664            // 512 KB refine list (cap NTOT)
// end = 925952

#define MARGIN 0.05f

typedef __attribute__((ext_vector_type(8))) short short8v;
typedef __attribute__((ext_vector_type(4))) float f32x4;

__device__ __forceinline__ unsigned short rne16(float f) {
    unsigned u = __float_as_uint(f);
    unsigned r = (u + 0x7FFFu + ((u >> 16) & 1u)) >> 16;  // RNE to bf16 bits
    return (unsigned short)r;
}

// ---------------------------------------------------------------------------
// K0: init NEA = 0.99*ea; e2 = ||e||^2; bf16 hi/lo codebook in fragment
// layout hiT/loT[q][code][8] (q = k/8); zero scalars.
// ---------------------------------------------------------------------------
__global__ __launch_bounds__(256) void k_init(
    const float* __restrict__ emb, const float* __restrict__ ea,
    float* __restrict__ out, float* __restrict__ e2,
    short* __restrict__ hiT, short* __restrict__ loT,
    double* __restrict__ loss, int* __restrict__ ctr)
{
    int j = blockIdx.x * 256 + threadIdx.x;   // 0..65535
    out[O_NEA + j] = 0.99f * ea[j];
    if (j < KCB) {
        const float* er = emb + j * DCV;
        float s = 0.f;
        #pragma unroll
        for (int d = 0; d < DCV; ++d) { float v = er[d]; s = fmaf(v, v, s); }
        e2[j] = s;
    }
    if (j < 8192) {
        int code = j >> 3, q = j & 7;
        const float* src = emb + code * DCV + q * 8;
        short8v h, l;
        #pragma unroll
        for (int t = 0; t < 8; ++t) {
            float x = src[t];
            unsigned short hb = rne16(x);
            float xh = __uint_as_float(((unsigned)hb) << 16);
            h[t] = (short)hb;
            l[t] = (short)rne16(x - xh);
        }
        *(short8v*)(hiT + (size_t)(q * KCB + code) * 8) = h;
        *(short8v*)(loT + (size_t)(q * KCB + code) * 8) = l;
    }
    if (j == 0) { *loss = 0.0; *ctr = 0; }
}

// ---------------------------------------------------------------------------
// K1: MFMA distance argmin. Block = 128 rows (4 waves x 32 rows). 128-code
// LDS chunks; 12 mfma_f32_16x16x32_bf16 per 16-code subchunk (hi*hi, hi*lo,
// lo*hi). Per-lane (best, second, idx); cross-lane merge; near-ties (gap <
// MARGIN) flagged for fp64 refine. Indices stored as float in out[O_IDX].
// ---------------------------------------------------------------------------
__global__ __launch_bounds__(256, 4) void k_dist(
    const float* __restrict__ ze, const short* __restrict__ hiT,
    const short* __restrict__ loT, const float* __restrict__ e2g,
    float* __restrict__ out, int* __restrict__ ctr, int* __restrict__ rlist)
{
    __shared__ short ldsH[8 * 128 * 8];   // 16 KB
    __shared__ short ldsL[8 * 128 * 8];   // 16 KB
    __shared__ float e2s[KCB];

    int tid  = threadIdx.x;
    int lane = tid & 63, w = tid >> 6;
    int g = lane >> 4, c = lane & 15;

    for (int i = tid; i < KCB; i += 256) e2s[i] = e2g[i];

    // A-fragments: row = lane&15, k = kh*32 + 8*(lane>>4) + j (same bijection as B)
    int rowbase = blockIdx.x * 128 + w * 32;
    short8v ahi[2][2], alo[2][2];
    #pragma unroll
    for (int t = 0; t < 2; ++t) {
        int n = rowbase + t * 16 + c;
        const float* base = ze + (size_t)(n >> 12) * CHW + (n & 4095);
        #pragma unroll
        for (int kh = 0; kh < 2; ++kh) {
            #pragma unroll
            for (int j = 0; j < 8; ++j) {
                int k = kh * 32 + g * 8 + j;
                float x = base[(size_t)k * HWN];
                unsigned short hb = rne16(x);
                float xh = __uint_as_float(((unsigned)hb) << 16);
                ahi[t][kh][j] = (short)hb;
                alo[t][kh][j] = (short)rne16(x - xh);
            }
        }
    }

    float best[8], second[8];
    int   bidx[8];
    #pragma unroll
    for (int i = 0; i < 8; ++i) { best[i] = 3.4e38f; second[i] = 3.4e38f; bidx[i] = 0; }

    for (int ch = 0; ch < 8; ++ch) {
        __syncthreads();
        #pragma unroll
        for (int r = 0; r < 8; ++r) {
            int u = r * 256 + tid;        // 0..2047 16B units
            int arr = u >> 10;
            int rest = u & 1023;          // q*128 + lc
            int q = rest >> 7, lc = rest & 127;
            const short* s = (arr ? loT : hiT) + (size_t)(q * KCB + ch * 128 + lc) * 8;
            short* d = (arr ? ldsL : ldsH) + rest * 8;
            *(short8v*)d = *(const short8v*)s;
        }
        __syncthreads();

        #pragma unroll 1
        for (int sub = 0; sub < 8; ++sub) {
            int boff = (sub * 16 + c) * 8;
            short8v bh0 = *(const short8v*)&ldsH[(g * 128) * 8 + boff];
            short8v bh1 = *(const short8v*)&ldsH[((4 + g) * 128) * 8 + boff];
            short8v bl0 = *(const short8v*)&ldsL[(g * 128) * 8 + boff];
            short8v bl1 = *(const short8v*)&ldsL[((4 + g) * 128) * 8 + boff];

            f32x4 a0 = {0.f, 0.f, 0.f, 0.f}, a1 = {0.f, 0.f, 0.f, 0.f};
            a0 = __builtin_amdgcn_mfma_f32_16x16x32_bf16(ahi[0][0], bh0, a0, 0, 0, 0);
            a1 = __builtin_amdgcn_mfma_f32_16x16x32_bf16(ahi[1][0], bh0, a1, 0, 0, 0);
            a0 = __builtin_amdgcn_mfma_f32_16x16x32_bf16(ahi[0][1], bh1, a0, 0, 0, 0);
            a1 = __builtin_amdgcn_mfma_f32_16x16x32_bf16(ahi[1][1], bh1, a1, 0, 0, 0);
            a0 = __builtin_amdgcn_mfma_f32_16x16x32_bf16(ahi[0][0], bl0, a0, 0, 0, 0);
            a1 = __builtin_amdgcn_mfma_f32_16x16x32_bf16(ahi[1][0], bl0, a1, 0, 0, 0);
            a0 = __builtin_amdgcn_mfma_f32_16x16x32_bf16(ahi[0][1], bl1, a0, 0, 0, 0);
            a1 = __builtin_amdgcn_mfma_f32_16x16x32_bf16(ahi[1][1], bl1, a1, 0, 0, 0);
            a0 = __builtin_amdgcn_mfma_f32_16x16x32_bf16(alo[0][0], bh0, a0, 0, 0, 0);
            a1 = __builtin_amdgcn_mfma_f32_16x16x32_bf16(alo[1][0], bh0, a1, 0, 0, 0);
            a0 = __builtin_amdgcn_mfma_f32_16x16x32_bf16(alo[0][1], bh1, a0, 0, 0, 0);
            a1 = __builtin_amdgcn_mfma_f32_16x16x32_bf16(alo[1][1], bh1, a1, 0, 0, 0);

            float e2v = e2s[ch * 128 + sub * 16 + c];
            int  code = ch * 128 + sub * 16 + c;
            #pragma unroll
            for (int t = 0; t < 2; ++t) {
                f32x4 av = t ? a1 : a0;
                #pragma unroll
                for (int r = 0; r < 4; ++r) {
                    int i = t * 4 + r;
                    float s = fmaf(-2.f, av[r], e2v);   // dist - x^2 (row-const drop)
                    bool lb = s < best[i];
                    bool ls = s < second[i];
                    second[i] = lb ? best[i] : (ls ? s : second[i]);
                    best[i]   = lb ? s : best[i];
                    bidx[i]   = lb ? code : bidx[i];
                }
            }
        }
    }

    #pragma unroll
    for (int i = 0; i < 8; ++i) {
        float b = best[i], s2 = second[i];
        int bi = bidx[i];
        #pragma unroll
        for (int m = 1; m < 16; m <<= 1) {
            float ob = __shfl_xor(b, m, 64);
            float os = __shfl_xor(s2, m, 64);
            int   oi = __shfl_xor(bi, m, 64);
            float ns = fminf(fmaxf(b, ob), fminf(s2, os));
            bi = (ob < b || (ob == b && oi < bi)) ? oi : bi;
            b  = fminf(b, ob);
            s2 = ns;
        }
        if (c == 0) {
            int t = i >> 2, r = i & 3;
            int n = rowbase + t * 16 + g * 4 + r;
            out[O_IDX + n] = (float)bi;
            if (s2 - b < MARGIN) { int p = atomicAdd(ctr, 1); rlist[p] = n; }
        }
    }
}

// ---------------------------------------------------------------------------
// K2: fp64 exact argmin for flagged near-tie vectors. One wave per candidate.
// ---------------------------------------------------------------------------
__global__ __launch_bounds__(256) void k_refine(
    const float* __restrict__ ze, const float* __restrict__ emb,
    float* __restrict__ out, const int* __restrict__ ctr,
    const int* __restrict__ rlist)
{
    int lane = threadIdx.x & 63;
    int gw   = (blockIdx.x * blockDim.x + threadIdx.x) >> 6;
    int nw   = (gridDim.x * blockDim.x) >> 6;
    int cnt  = *ctr;

    for (int i = gw; i < cnt; i += nw) {
        int n  = rlist[i];
        const float* zp = ze + (size_t)(n >> 12) * CHW + (n & 4095);
        float x[DCV];
        #pragma unroll
        for (int d = 0; d < DCV; ++d) x[d] = zp[(size_t)d * HWN];  // uniform -> broadcast

        double bd = 1e300;
        int    bi = 0;
        #pragma unroll 1
        for (int cc = 0; cc < KCB / 64; ++cc) {
            int k = cc * 64 + lane;
            const float* eb = emb + k * DCV;
            double a0 = 0.0, a1 = 0.0;
            #pragma unroll
            for (int d = 0; d < DCV; d += 2) {
                double d0 = (double)x[d]     - (double)eb[d];
                double d1 = (double)x[d + 1] - (double)eb[d + 1];
                a0 = fma(d0, d0, a0);
                a1 = fma(d1, d1, a1);
            }
            double dist = a0 + a1;
            if (dist < bd || (dist == bd && k < bi)) { bd = dist; bi = k; }
        }
        #pragma unroll
        for (int off = 32; off > 0; off >>= 1) {
            double od = __shfl_xor(bd, off, 64);
            int    oi = __shfl_xor(bi, off, 64);
            if (od < bd || (od == bd && oi < bi)) { bd = od; bi = oi; }
        }
        if (lane == 0) out[O_IDX + n] = (float)bi;
    }
}

// ---------------------------------------------------------------------------
// K3: finalize: z_q_st write, commitment-loss partials (reads final indices).
// ---------------------------------------------------------------------------
__global__ __launch_bounds__(256) void k_final(
    const float* __restrict__ ze, const float* __restrict__ emb,
    float* __restrict__ out, double* __restrict__ loss)
{
    int n  = blockIdx.x * 256 + threadIdx.x;
    int best = (int)out[O_IDX + n];

    const float* zp = ze + (size_t)(n >> 12) * CHW + (n & 4095);
    const float4* er4 = (const float4*)(emb + best * DCV);
    float er[DCV];
    #pragma unroll
    for (int q = 0; q < DCV / 4; ++q) {
        float4 v = er4[q];
        er[q * 4 + 0] = v.x; er[q * 4 + 1] = v.y;
        er[q * 4 + 2] = v.z; er[q * 4 + 3] = v.w;
    }

    float* zq = out + O_ZQ + (size_t)(n >> 12) * CHW + (n & 4095);
    float lp = 0.f;
    #pragma unroll
    for (int d = 0; d < DCV; ++d) {
        float x  = zp[(size_t)d * HWN];
        float df = x - er[d];
        lp = fmaf(df, df, lp);
        zq[(size_t)d * HWN] = x + (er[d] - x);  // straight-through f32 rounding
    }

    #pragma unroll
    for (int off = 32; off > 0; off >>= 1) lp += __shfl_down(lp, off, 64);

    __shared__ float wsum[4];
    int lane = threadIdx.x & 63, wid = threadIdx.x >> 6;
    if (lane == 0) wsum[wid] = lp;
    __syncthreads();
    if (threadIdx.x == 0) {
        double s = (double)wsum[0] + wsum[1] + wsum[2] + wsum[3];
        atomicAdd(loss, s);
    }
}

// ---------------------------------------------------------------------------
// K4: segment-sum partials in LDS; atomic flush 0.01*dw into NEA.
// gidx==0 blocks also produce per-batch count partials.
// ---------------------------------------------------------------------------
__global__ __launch_bounds__(256) void k_dw_part(
    const float* __restrict__ ze, const float* __restrict__ outIdx,
    float* __restrict__ partc, float* __restrict__ out)
{
    int gidx = blockIdx.x >> 5, b = blockIdx.x & 31;
    __shared__ float acc[8 * KCB];
    __shared__ float cnt[KCB];
    for (int i = threadIdx.x; i < 8 * KCB; i += 256) acc[i] = 0.f;
    if (gidx == 0) for (int i = threadIdx.x; i < KCB; i += 256) cnt[i] = 0.f;
    __syncthreads();

    const float* zp  = ze + (size_t)b * CHW + (size_t)gidx * 8 * HWN;
    const float* ipf = outIdx + b * HWN;
    for (int hw = threadIdx.x; hw < HWN; hw += 256) {
        int idx = (int)ipf[hw];
        #pragma unroll
        for (int i = 0; i < 8; ++i) atomicAdd(&acc[i * KCB + idx], zp[(size_t)i * HWN + hw]);
        if (gidx == 0) atomicAdd(&cnt[idx], 1.f);
    }
    __syncthreads();

    for (int j = threadIdx.x; j < 8192; j += 256) {
        int k = j >> 3, i = j & 7;
        float v = acc[i * KCB + k];
        if (v != 0.f) atomicAdd(&out[O_NEA + k * DCV + gidx * 8 + i], 0.01f * v);
    }
    if (gidx == 0)
        for (int k = threadIdx.x; k < KCB; k += 256) partc[b * KCB + k] = cnt[k];
}

// ---------------------------------------------------------------------------
// K5: counts EMA + n + smoothed denom + loss scalar
// ---------------------------------------------------------------------------
__global__ __launch_bounds__(1024) void k_stats(
    const float* __restrict__ cs, const float* __restrict__ partc,
    float* __restrict__ out, float* __restrict__ sm,
    const double* __restrict__ loss)
{
    int k = threadIdx.x;
    float csum = 0.f;
    #pragma unroll
    for (int b = 0; b < 32; ++b) csum += partc[b * KCB + k];
    float ncs = fmaf(0.01f, csum, 0.99f * cs[k]);
    out[O_NCS + k] = ncs;

    __shared__ float red[KCB];
    red[k] = ncs;
    __syncthreads();
    for (int s = 512; s > 0; s >>= 1) {
        if (k < s) red[k] += red[k + s];
        __syncthreads();
    }
    float n = red[0];
    sm[k] = (ncs + 1e-5f) / (n + (float)KCB * 1e-5f) * n;
    if (k == 0) out[O_LOSS] = (float)(0.25 * (*loss) / (double)(NTOT * DCV));
}

// K6: new_embedding = new_embed_avg / smoothed[k]
__global__ __launch_bounds__(256) void k_embed(
    float* __restrict__ out, const float* __restrict__ sm)
{
    int j = blockIdx.x * 256 + threadIdx.x;
    out[O_NE + j] = out[O_NEA + j] / sm[j >> 6];
}

// ---------------------------------------------------------------------------
extern "C" void kernel_launch(void* const* d_in, const int* in_sizes, int n_in,
                              void* d_out, int out_size, void* d_ws, size_t ws_size,
                              hipStream_t stream)
{
    const float* ze  = (const float*)d_in[0];
    const float* emb = (const float*)d_in[1];
    const float* cs  = (const float*)d_in[2];
    const float* ea  = (const float*)d_in[3];
    float* out = (float*)d_out;

    char*   w     = (char*)d_ws;
    double* loss  = (double*)(w + W_LOSS);
    int*    ctr   = (int*)(w + W_CTR);
    float*  e2    = (float*)(w + W_E2);
    float*  sm    = (float*)(w + W_SM);
    short*  hiT   = (short*)(w + W_HIT);
    short*  loT   = (short*)(w + W_LOT);
    float*  partc = (float*)(w + W_PARTC);
    int*    rlist = (int*)(w + W_RLIST);

    k_init   <<<256, 256, 0, stream>>>(emb, ea, out, e2, hiT, loT, loss, ctr);
    k_dist   <<<1024, 256, 0, stream>>>(ze, hiT, loT, e2, out, ctr, rlist);
    k_refine <<<256, 256, 0, stream>>>(ze, emb, out, ctr, rlist);
    k_final  <<<NTOT / 256, 256, 0, stream>>>(ze, emb, out, loss);
    k_dw_part<<<256, 256, 0, stream>>>(ze, (const float*)(out + O_IDX), partc, out);
    k_stats  <<<1, 1024, 0, stream>>>(cs, partc, out, sm, loss);
    k_embed  <<<256, 256, 0, stream>>>(out, sm);
}